// Round 8
// baseline (340.682 us; speedup 1.0000x reference)
//
#include <hip/hip_runtime.h>
#include <stdint.h>

#define NROW 4096
#define NDIM 128
#define KNEG 4092
#define INF_VAL 1e30f
#define BUCKETS 2048
#define PLO 384
#define PHI 3712
#define GTOT ((size_t)NROW * (size_t)KNEG)   // 16,760,832 = 4092 * 4096

typedef __attribute__((ext_vector_type(8))) short short8;
typedef __attribute__((ext_vector_type(4))) float f32x4;

// ---------------- Threefry-2x32-20, key = (0, 42) ----------------
__device__ __forceinline__ uint32_t rotl32(uint32_t v, int d) {
  return (v << d) | (v >> (32 - d));
}

__device__ __forceinline__ void threefry2x32(uint32_t x0, uint32_t x1,
                                             uint32_t& y0, uint32_t& y1) {
  const uint32_t k0 = 0u, k1 = 42u;
  const uint32_t k2 = 0x1BD11BDAu ^ k0 ^ k1;
  uint32_t v0 = x0 + k0, v1 = x1 + k1;
#define TF_R(r) v0 += v1; v1 = rotl32(v1, r); v1 ^= v0;
  TF_R(13) TF_R(15) TF_R(26) TF_R(6)
  v0 += k1; v1 += k2 + 1u;
  TF_R(17) TF_R(29) TF_R(16) TF_R(24)
  v0 += k2; v1 += k0 + 2u;
  TF_R(13) TF_R(15) TF_R(26) TF_R(6)
  v0 += k0; v1 += k1 + 3u;
  TF_R(17) TF_R(29) TF_R(16) TF_R(24)
  v0 += k1; v1 += k2 + 4u;
  TF_R(13) TF_R(15) TF_R(26) TF_R(6)
  v0 += k2; v1 += k0 + 5u;
#undef TF_R
  y0 = v0; y1 = v1;
}

// partitionable threefry, bits = y1 — verified R1; __logf verified R3
__device__ __forceinline__ float gumbel_ref(uint32_t f) {
  uint32_t y0, y1;
  threefry2x32(0u, f, y0, y1);
  uint32_t m = y1 >> 9;
  float u;
  if (m == 0u) u = 1.17549435e-38f;
  else u = __uint_as_float(m | 0x3f800000u) - 1.0f;
  return -__logf(-__logf(u));
}

__device__ __forceinline__ float softplus_ref(float x) {
  return fmaxf(x, 0.0f) + log1pf(expf(-fabsf(x)));
}

// linear-in-z monotone key (5 instr). Float-clamp BEFORE cvt so INF -> 2047.
__device__ __forceinline__ int bucket_lin(float x, float mean, float invw) {
  float b = (x - mean) * invw + 1024.0f;
  b = fminf(fmaxf(b, 0.0f), 2047.0f);
  return (int)b;
}

// ---------------- kernel A: sumsq + fp32->bf16 convert + acc zero ----------------
__global__ __launch_bounds__(64) void prep_kernel(const float* __restrict__ X,
                                                  float* __restrict__ sq,
                                                  ushort* __restrict__ Xbf,
                                                  double* __restrict__ acc) {
  int i = blockIdx.x;
  int lane = threadIdx.x;
  if (i == 0 && lane < 4) acc[lane] = 0.0;
  float2 v = ((const float2*)(X + (size_t)i * NDIM))[lane];
  float s = v.x * v.x + v.y * v.y;
  for (int o = 32; o > 0; o >>= 1) s += __shfl_down(s, o);
  if (lane == 0) sq[i] = s;
  uint32_t ux = __float_as_uint(v.x);
  uint32_t uy = __float_as_uint(v.y);
  ux += 0x7fffu + ((ux >> 16) & 1u);
  uy += 0x7fffu + ((uy >> 16) & 1u);
  ushort2 h;
  h.x = (ushort)(ux >> 16);
  h.y = (ushort)(uy >> 16);
  ((ushort2*)(Xbf + (size_t)i * NDIM))[lane] = h;
}

// ---------------- kernel A2: dense Gumbel table (data-independent) ----------------
// 4092 blocks x 4096 entries each (256 thr x 4 float4). Exact cover of GTOT:
// f0 = blk*4096 + q*1024 + tid*4  (R7 bug: stride was q*4096 -> 75% uninit).
__global__ __launch_bounds__(256) void gumbel_kernel(float* __restrict__ g) {
  uint32_t b0 = (uint32_t)blockIdx.x * 4096u;
#pragma unroll
  for (int q = 0; q < 4; ++q) {
    uint32_t f0 = b0 + (uint32_t)q * 1024u + (uint32_t)threadIdx.x * 4u;
    float4 v;
    v.x = gumbel_ref(f0 + 0u);
    v.y = gumbel_ref(f0 + 1u);
    v.z = gumbel_ref(f0 + 2u);
    v.w = gumbel_ref(f0 + 3u);
    *(float4*)(g + f0) = v;
  }
}

// ---------------- kernel B: distance matrix via bf16 MFMA ----------------
#define DSTR 68
__global__ __launch_bounds__(256) void dist_mfma(const ushort* __restrict__ Xbf,
                                                 const float* __restrict__ sq,
                                                 float* __restrict__ dist) {
  __shared__ ushort Als[128 * DSTR];
  __shared__ ushort Bls[128 * DSTR];
  const int tid = threadIdx.x;
  const int wave = tid >> 6, lane = tid & 63;
  const int q = lane >> 4, ln = lane & 15;
  const int bi = blockIdx.y, bj = blockIdx.x;
  const ushort* Ag = Xbf + (size_t)bi * 128 * NDIM;
  const ushort* Bg = Xbf + (size_t)bj * 128 * NDIM;

  f32x4 acc[8][2];
#pragma unroll
  for (int mt = 0; mt < 8; ++mt)
#pragma unroll
    for (int nt = 0; nt < 2; ++nt) acc[mt][nt] = (f32x4){0.f, 0.f, 0.f, 0.f};

  for (int kh = 0; kh < 2; ++kh) {
    if (kh) __syncthreads();
#pragma unroll
    for (int t = 0; t < 4; ++t) {
      int c = tid + 256 * t;
      int r = c >> 3, k8 = (c & 7) << 3;
      *(short8*)&Als[r * DSTR + k8] =
          *(const short8*)(Ag + (size_t)r * NDIM + kh * 64 + k8);
      *(short8*)&Bls[r * DSTR + k8] =
          *(const short8*)(Bg + (size_t)r * NDIM + kh * 64 + k8);
    }
    __syncthreads();
#pragma unroll
    for (int k0 = 0; k0 < 64; k0 += 32) {
      int kf = k0 + q * 8;
      short8 a[8], b[2];
#pragma unroll
      for (int mt = 0; mt < 8; ++mt)
        a[mt] = *(const short8*)&Als[(mt * 16 + ln) * DSTR + kf];
#pragma unroll
      for (int nt = 0; nt < 2; ++nt)
        b[nt] = *(const short8*)&Bls[(wave * 32 + nt * 16 + ln) * DSTR + kf];
#pragma unroll
      for (int mt = 0; mt < 8; ++mt)
#pragma unroll
        for (int nt = 0; nt < 2; ++nt)
          acc[mt][nt] = __builtin_amdgcn_mfma_f32_16x16x32_bf16(
              a[mt], b[nt], acc[mt][nt], 0, 0, 0);
    }
  }

  float sqj[2];
#pragma unroll
  for (int nt = 0; nt < 2; ++nt)
    sqj[nt] = sq[bj * 128 + wave * 32 + nt * 16 + ln];
#pragma unroll
  for (int mt = 0; mt < 8; ++mt) {
    int ibase = bi * 128 + mt * 16 + q * 4;
#pragma unroll
    for (int r = 0; r < 4; ++r) {
      int i = ibase + r;
      float sqi = sq[i];
#pragma unroll
      for (int nt = 0; nt < 2; ++nt) {
        int j = bj * 128 + wave * 32 + nt * 16 + ln;
        float d = sqi + sqj[nt] - 2.0f * acc[mt][nt][r];
        dist[(size_t)i * NROW + j] = sqrtf(fmaxf(d, 1e-12f));
      }
    }
  }
}

// ---------------- kernel C: per-row rank + sample + loss ----------------
// rank = scatter position (exact across buckets); exact within-bucket rank
// resolved only in contiguous tail ranges [0,PLO) / [PHI,4096).
// Gumbel comes from the precomputed table G (coalesced: rank ~= p), or is
// computed inline if G==nullptr (workspace fallback).
__global__ __launch_bounds__(256) void row_kernel(const float* __restrict__ dist,
                                                  const float* __restrict__ G,
                                                  double* __restrict__ acc) {
  __shared__ alignas(16) float sorted[NROW];   // 16 KB
  __shared__ alignas(16) int base[BUCKETS];    // 8 KB (bucket ENDs after scatter)
  __shared__ float wredf[8];
  __shared__ int wtot[4];
  __shared__ float s_pos[3];
  __shared__ float s_sel[3];

  // aliases — live only after the rank/score pass (barrier-separated)
  float* cscore = (float*)base;            // 768 (base: 2048 int slots)
  float* cx     = (float*)base + 768;      // 768
  int*   crank  = (int*)sorted;            // 768 (sorted: 4096 slots)
  float* redf   = sorted + 1024;           // 256
  int*   redi   = (int*)(sorted + 1280);   // 256
  int*   redi2  = (int*)(sorted + 1536);   // 256

  const int i = blockIdx.x;
  const int tid = threadIdx.x;
  const int lane = tid & 63, wid = tid >> 6;
  const float* row = dist + (size_t)i * NROW;

  // ---- load 16 values, mask same-class block to INF ----
  float x[16];
  {
    const float4* r4 = (const float4*)row;
#pragma unroll
    for (int q4 = 0; q4 < 4; ++q4) {
      float4 f = r4[tid * 4 + q4];
      x[q4 * 4 + 0] = f.x; x[q4 * 4 + 1] = f.y;
      x[q4 * 4 + 2] = f.z; x[q4 * 4 + 3] = f.w;
    }
  }
#pragma unroll
  for (int qq = 0; qq < 16; ++qq) {
    int j = tid * 16 + qq;
    if ((j >> 2) == (i >> 2)) x[qq] = INF_VAL;
  }

  // ---- positives ----
  if (tid == 0) {
    int gbase = i & ~3;
    float p[3]; int np = 0;
    for (int qq = 0; qq < 4; ++qq) {
      int j = gbase + qq;
      if (j != i) p[np++] = row[j];
    }
    float a = p[0], b = p[1], c = p[2], t_;
    if (a > b) { t_ = a; a = b; b = t_; }
    if (b > c) { t_ = b; b = c; c = t_; }
    if (a > b) { t_ = a; a = b; b = t_; }
    s_pos[0] = a; s_pos[1] = b; s_pos[2] = c;
  }

  // ---- mean ----
  float ls = 0.f;
#pragma unroll
  for (int qq = 0; qq < 16; ++qq) if (x[qq] < 1e29f) ls += x[qq];
  for (int o = 32; o > 0; o >>= 1) ls += __shfl_down(ls, o);
  if (lane == 0) wredf[wid] = ls;
  __syncthreads();
  const float negsum = wredf[0] + wredf[1] + wredf[2] + wredf[3];
  const float mean = negsum / (float)KNEG;

  // ---- variance (two-pass, matches ref) ----
  float ls2 = 0.f;
#pragma unroll
  for (int qq = 0; qq < 16; ++qq)
    if (x[qq] < 1e29f) { float z = x[qq] - mean; ls2 += z * z; }
  for (int o = 32; o > 0; o >>= 1) ls2 += __shfl_down(ls2, o);
  if (lane == 0) wredf[4 + wid] = ls2;
  __syncthreads();
  const float var = (wredf[4] + wredf[5] + wredf[6] + wredf[7]) / (float)KNEG;
  const float stdv = sqrtf(var);
  const float rdenom = __frcp_rn(2.0f * stdv * stdv);
  const float invw = 256.0f / stdv;   // +-4 sigma across 2048 buckets

  // ---- histogram (linear buckets) ----
  {
    int4* b4 = (int4*)base;
    b4[tid] = (int4){0, 0, 0, 0};
    b4[tid + 256] = (int4){0, 0, 0, 0};
  }
  __syncthreads();
  int bkt[16];
#pragma unroll
  for (int qq = 0; qq < 16; ++qq) {
    bkt[qq] = bucket_lin(x[qq], mean, invw);
    atomicAdd(&base[bkt[qq]], 1);
  }
  __syncthreads();

  // ---- exclusive scan over 2048 buckets (8/thread + wave shfl) ----
  int c8[8]; int lsum = 0;
#pragma unroll
  for (int qq = 0; qq < 8; ++qq) {
    int t_ = base[tid * 8 + qq];
    c8[qq] = lsum; lsum += t_;
  }
  int incl = lsum;
  for (int off = 1; off < 64; off <<= 1) {
    int o = __shfl_up(incl, off);
    if (lane >= off) incl += o;
  }
  if (lane == 63) wtot[wid] = incl;
  __syncthreads();
  int excl = incl - lsum;
#pragma unroll
  for (int w = 0; w < 4; ++w) if (w < wid) excl += wtot[w];
#pragma unroll
  for (int qq = 0; qq < 8; ++qq) base[tid * 8 + qq] = excl + c8[qq];
  __syncthreads();

  // ---- scatter (base[b] becomes bucket END) ----
#pragma unroll
  for (int qq = 0; qq < 16; ++qq) {
    int p = atomicAdd(&base[bkt[qq]], 1);
    sorted[p] = x[qq];
  }
  __syncthreads();

  // ---- rank/score/top-3 ----
  const uint32_t fbase = (uint32_t)i * (uint32_t)KNEG;
  const float* grow = G ? (G + fbase) : nullptr;
  float t0s = -1e38f, t1s = -1e38f, t2s = -1e38f;
  int   t0r = 0x7fffffff, t1r = 0x7fffffff, t2r = 0x7fffffff;
  float t0x = 0.f, t1x = 0.f, t2x = 0.f;
#pragma unroll
  for (int qq = 0; qq < 16; ++qq) {
    int p = tid + 256 * qq;
    float xv = sorted[p];
    int rank = p;
    // only qq 0,1,14,15 can ever hit the tail ranges — fold the guard away
    // for the other 12 unrolled iterations at compile time
    if ((qq <= 1 || qq >= 14) && (p < PLO || p >= PHI)) {
      int b = bucket_lin(xv, mean, invw);
      int s0 = (b == 0) ? 0 : base[b - 1];
      int e0 = base[b];
      int c = 0;
      for (int u = s0; u < e0; ++u) {
        float o = sorted[u];
        c += (o < xv || (o == xv && u < p)) ? 1 : 0;
      }
      rank = s0 + c;
    }
    if (rank < KNEG) {
      float z = xv - mean;
      float gv = grow ? grow[rank] : gumbel_ref(fbase + (uint32_t)rank);
      float sv = fmaf(z * z, rdenom, gv);
      if (sv > t2s || (sv == t2s && rank < t2r)) {
        t2s = sv; t2r = rank; t2x = xv;
        if (t2s > t1s || (t2s == t1s && t2r < t1r)) {
          float ts = t1s; int tr = t1r; float tx = t1x;
          t1s = t2s; t1r = t2r; t1x = t2x; t2s = ts; t2r = tr; t2x = tx;
        }
        if (t1s > t0s || (t1s == t0s && t1r < t0r)) {
          float ts = t0s; int tr = t0r; float tx = t0x;
          t0s = t1s; t0r = t1r; t0x = t1x; t1s = ts; t1r = tr; t1x = tx;
        }
      }
    }
  }
  __syncthreads();  // sorted/base reads done; aliases become live

  cscore[tid * 3 + 0] = t0s; crank[tid * 3 + 0] = t0r; cx[tid * 3 + 0] = t0x;
  cscore[tid * 3 + 1] = t1s; crank[tid * 3 + 1] = t1r; cx[tid * 3 + 1] = t1x;
  cscore[tid * 3 + 2] = t2s; crank[tid * 3 + 2] = t2r; cx[tid * 3 + 2] = t2x;
  __syncthreads();

  // ---- block top-3 over 768 candidates (score desc, rank asc) ----
  for (int t = 0; t < 3; ++t) {
    float bs = -1e38f; int br = 0x7fffffff; int bidx = 0;
    for (int k = tid; k < 768; k += 256) {
      float s_ = cscore[k]; int r_ = crank[k];
      if (s_ > bs || (s_ == bs && r_ < br)) { bs = s_; br = r_; bidx = k; }
    }
    redf[tid] = bs; redi[tid] = br; redi2[tid] = bidx;
    __syncthreads();
    if (tid < 64) {
      float s0_ = redf[tid]; int r0_ = redi[tid]; int i0_ = redi2[tid];
#pragma unroll
      for (int o = 64; o < 256; o += 64) {
        float s1 = redf[tid + o]; int r1 = redi[tid + o];
        if (s1 > s0_ || (s1 == s0_ && r1 < r0_)) {
          s0_ = s1; r0_ = r1; i0_ = redi2[tid + o];
        }
      }
      for (int off = 32; off > 0; off >>= 1) {
        float s1 = __shfl_down(s0_, off);
        int r1 = __shfl_down(r0_, off);
        int i1 = __shfl_down(i0_, off);
        if (s1 > s0_ || (s1 == s0_ && r1 < r0_)) { s0_ = s1; r0_ = r1; i0_ = i1; }
      }
      if (tid == 0) { s_sel[t] = cx[i0_]; cscore[i0_] = -1e38f; }
    }
    __syncthreads();
  }

  // ---- epilogue ----
  if (tid == 0) {
    float p0 = s_pos[0], p1 = s_pos[1], p2 = s_pos[2];
    float thr = p2 + 0.05f;
    float samp[3]; bool kept[3]; int cnt = 0;
#pragma unroll
    for (int t = 0; t < 3; ++t) {
      samp[t] = s_sel[t];
      kept[t] = samp[t] < thr;
      cnt += kept[t] ? 1 : 0;
    }
    bool any = cnt > 0;
    float pos_loss = 0.5f *
        (softplus_ref(-2.0f * (1.0f - p0)) + softplus_ref(-2.0f * (1.0f - p1)) +
         softplus_ref(-2.0f * (1.0f - p2))) / 3.0f;
    float nsum = 0.0f;
#pragma unroll
    for (int t = 0; t < 3; ++t)
      if (kept[t]) nsum += softplus_ref(20.0f * (1.0f - samp[t]));
    float neg_loss = 0.05f * nsum / (float)(cnt > 0 ? cnt : 1);
    float row_loss = any ? (pos_loss + neg_loss) : 0.0f;
    int first = kept[0] ? 0 : (kept[1] ? 1 : (kept[2] ? 2 : 0));
    float neg0 = samp[first];
    float errv = (any && (p0 < neg0 - 0.1f)) ? 1.0f : 0.0f;
    atomicAdd(acc + 0, (double)row_loss);
    atomicAdd(acc + 1, (double)errv);
    atomicAdd(acc + 2, (double)(p0 + p1 + p2));
    atomicAdd(acc + 3, (double)negsum);
  }
}

// ---------------- finalize ----------------
__global__ void finalize_kernel(const double* __restrict__ acc,
                                float* __restrict__ out) {
  out[0] = (float)(acc[0] / (double)NROW);
  out[1] = (float)(1.0 - acc[1] / (double)NROW);
  out[2] = (float)(acc[2] / ((double)NROW * 3.0));
  out[3] = (float)(acc[3] / ((double)NROW * (double)KNEG));
}

extern "C" void kernel_launch(void* const* d_in, const int* in_sizes, int n_in,
                              void* d_out, int out_size, void* d_ws, size_t ws_size,
                              hipStream_t stream) {
  (void)in_sizes; (void)n_in; (void)out_size;
  const float* X = (const float*)d_in[0];
  float* out = (float*)d_out;
  char* ws = (char*)d_ws;

  float* dist = (float*)ws;                                        // 64 MiB
  size_t off = (size_t)NROW * NROW * sizeof(float);
  float* sq = (float*)(ws + off);            off += NROW * sizeof(float);
  ushort* Xbf = (ushort*)(ws + off);         off += (size_t)NROW * NDIM * sizeof(ushort);
  double* acc = (double*)(ws + off);         off += 4 * sizeof(double);
  // Gumbel table (64 MB) — only if workspace allows; else inline fallback
  float* G = nullptr;
  if (ws_size >= off + GTOT * sizeof(float)) G = (float*)(ws + off);

  prep_kernel<<<NROW, 64, 0, stream>>>(X, sq, Xbf, acc);
  if (G) gumbel_kernel<<<KNEG, 256, 0, stream>>>(G);
  dim3 gb(NROW / 128, NROW / 128);
  dist_mfma<<<gb, 256, 0, stream>>>(Xbf, sq, dist);
  row_kernel<<<NROW, 256, 0, stream>>>(dist, G, acc);
  finalize_kernel<<<1, 1, 0, stream>>>(acc, out);
}

// Round 9
// 184.813 us; speedup vs baseline: 1.8434x; 1.8434x over previous
//
#include <hip/hip_runtime.h>
#include <stdint.h>

#define NROW 4096
#define NDIM 128
#define KNEG 4092
#define INF_VAL 1e30f
#define BUCKETS 2048
#define PLO 384
#define PHI 3712
#define GTOT ((size_t)NROW * (size_t)KNEG)   // 16,760,832 = 4092 * 4096

typedef __attribute__((ext_vector_type(8))) short short8;
typedef __attribute__((ext_vector_type(4))) float f32x4;

// ---------------- Threefry-2x32-20, key = (0, 42) ----------------
__device__ __forceinline__ uint32_t rotl32(uint32_t v, int d) {
  return (v << d) | (v >> (32 - d));
}

__device__ __forceinline__ void threefry2x32(uint32_t x0, uint32_t x1,
                                             uint32_t& y0, uint32_t& y1) {
  const uint32_t k0 = 0u, k1 = 42u;
  const uint32_t k2 = 0x1BD11BDAu ^ k0 ^ k1;
  uint32_t v0 = x0 + k0, v1 = x1 + k1;
#define TF_R(r) v0 += v1; v1 = rotl32(v1, r); v1 ^= v0;
  TF_R(13) TF_R(15) TF_R(26) TF_R(6)
  v0 += k1; v1 += k2 + 1u;
  TF_R(17) TF_R(29) TF_R(16) TF_R(24)
  v0 += k2; v1 += k0 + 2u;
  TF_R(13) TF_R(15) TF_R(26) TF_R(6)
  v0 += k0; v1 += k1 + 3u;
  TF_R(17) TF_R(29) TF_R(16) TF_R(24)
  v0 += k1; v1 += k2 + 4u;
  TF_R(13) TF_R(15) TF_R(26) TF_R(6)
  v0 += k2; v1 += k0 + 5u;
#undef TF_R
  y0 = v0; y1 = v1;
}

// partitionable threefry, bits = y1 — verified R1; __logf verified R3
__device__ __forceinline__ float gumbel_ref(uint32_t f) {
  uint32_t y0, y1;
  threefry2x32(0u, f, y0, y1);
  uint32_t m = y1 >> 9;
  float u;
  if (m == 0u) u = 1.17549435e-38f;
  else u = __uint_as_float(m | 0x3f800000u) - 1.0f;
  return -__logf(-__logf(u));
}

__device__ __forceinline__ float softplus_ref(float x) {
  return fmaxf(x, 0.0f) + log1pf(expf(-fabsf(x)));
}

// linear-in-z monotone key (5 instr). Float-clamp BEFORE cvt so INF -> 2047.
__device__ __forceinline__ int bucket_lin(float x, float mean, float invw) {
  float b = (x - mean) * invw + 1024.0f;
  b = fminf(fmaxf(b, 0.0f), 2047.0f);
  return (int)b;
}

// ---------------- kernel A: sumsq + fp32->bf16 convert ----------------
__global__ __launch_bounds__(64) void prep_kernel(const float* __restrict__ X,
                                                  float* __restrict__ sq,
                                                  ushort* __restrict__ Xbf) {
  int i = blockIdx.x;
  int lane = threadIdx.x;
  float2 v = ((const float2*)(X + (size_t)i * NDIM))[lane];
  float s = v.x * v.x + v.y * v.y;
  for (int o = 32; o > 0; o >>= 1) s += __shfl_down(s, o);
  if (lane == 0) sq[i] = s;
  uint32_t ux = __float_as_uint(v.x);
  uint32_t uy = __float_as_uint(v.y);
  ux += 0x7fffu + ((ux >> 16) & 1u);
  uy += 0x7fffu + ((uy >> 16) & 1u);
  ushort2 h;
  h.x = (ushort)(ux >> 16);
  h.y = (ushort)(uy >> 16);
  ((ushort2*)(Xbf + (size_t)i * NDIM))[lane] = h;
}

// ---------------- kernel A2: dense Gumbel table (data-independent) ----------------
// 4092 blocks x 4096 entries each (256 thr x 4 float4). Exact cover of GTOT.
__global__ __launch_bounds__(256) void gumbel_kernel(float* __restrict__ g) {
  uint32_t b0 = (uint32_t)blockIdx.x * 4096u;
#pragma unroll
  for (int q = 0; q < 4; ++q) {
    uint32_t f0 = b0 + (uint32_t)q * 1024u + (uint32_t)threadIdx.x * 4u;
    float4 v;
    v.x = gumbel_ref(f0 + 0u);
    v.y = gumbel_ref(f0 + 1u);
    v.z = gumbel_ref(f0 + 2u);
    v.w = gumbel_ref(f0 + 3u);
    *(float4*)(g + f0) = v;
  }
}

// ---------------- kernel B: distance matrix via bf16 MFMA ----------------
#define DSTR 68
__global__ __launch_bounds__(256) void dist_mfma(const ushort* __restrict__ Xbf,
                                                 const float* __restrict__ sq,
                                                 float* __restrict__ dist) {
  __shared__ ushort Als[128 * DSTR];
  __shared__ ushort Bls[128 * DSTR];
  const int tid = threadIdx.x;
  const int wave = tid >> 6, lane = tid & 63;
  const int q = lane >> 4, ln = lane & 15;
  const int bi = blockIdx.y, bj = blockIdx.x;
  const ushort* Ag = Xbf + (size_t)bi * 128 * NDIM;
  const ushort* Bg = Xbf + (size_t)bj * 128 * NDIM;

  f32x4 acc[8][2];
#pragma unroll
  for (int mt = 0; mt < 8; ++mt)
#pragma unroll
    for (int nt = 0; nt < 2; ++nt) acc[mt][nt] = (f32x4){0.f, 0.f, 0.f, 0.f};

  for (int kh = 0; kh < 2; ++kh) {
    if (kh) __syncthreads();
#pragma unroll
    for (int t = 0; t < 4; ++t) {
      int c = tid + 256 * t;
      int r = c >> 3, k8 = (c & 7) << 3;
      *(short8*)&Als[r * DSTR + k8] =
          *(const short8*)(Ag + (size_t)r * NDIM + kh * 64 + k8);
      *(short8*)&Bls[r * DSTR + k8] =
          *(const short8*)(Bg + (size_t)r * NDIM + kh * 64 + k8);
    }
    __syncthreads();
#pragma unroll
    for (int k0 = 0; k0 < 64; k0 += 32) {
      int kf = k0 + q * 8;
      short8 a[8], b[2];
#pragma unroll
      for (int mt = 0; mt < 8; ++mt)
        a[mt] = *(const short8*)&Als[(mt * 16 + ln) * DSTR + kf];
#pragma unroll
      for (int nt = 0; nt < 2; ++nt)
        b[nt] = *(const short8*)&Bls[(wave * 32 + nt * 16 + ln) * DSTR + kf];
#pragma unroll
      for (int mt = 0; mt < 8; ++mt)
#pragma unroll
        for (int nt = 0; nt < 2; ++nt)
          acc[mt][nt] = __builtin_amdgcn_mfma_f32_16x16x32_bf16(
              a[mt], b[nt], acc[mt][nt], 0, 0, 0);
    }
  }

  float sqj[2];
#pragma unroll
  for (int nt = 0; nt < 2; ++nt)
    sqj[nt] = sq[bj * 128 + wave * 32 + nt * 16 + ln];
#pragma unroll
  for (int mt = 0; mt < 8; ++mt) {
    int ibase = bi * 128 + mt * 16 + q * 4;
#pragma unroll
    for (int r = 0; r < 4; ++r) {
      int i = ibase + r;
      float sqi = sq[i];
#pragma unroll
      for (int nt = 0; nt < 2; ++nt) {
        int j = bj * 128 + wave * 32 + nt * 16 + ln;
        float d = sqi + sqj[nt] - 2.0f * acc[mt][nt][r];
        dist[(size_t)i * NROW + j] = sqrtf(fmaxf(d, 1e-12f));
      }
    }
  }
}

// ---------------- kernel C: per-row rank + sample + loss ----------------
// Per-block result goes to part[blockIdx] (zero-contention float4 store);
// R8's 4 same-address f64 atomics x 4096 blocks were the suspected
// completion-rate governor (~230us floor insensitive to all internal opts).
__global__ __launch_bounds__(256) void row_kernel(const float* __restrict__ dist,
                                                  const float* __restrict__ G,
                                                  float4* __restrict__ part) {
  __shared__ alignas(16) float sorted[NROW];   // 16 KB
  __shared__ alignas(16) int base[BUCKETS];    // 8 KB (bucket ENDs after scatter)
  __shared__ float wredf[8];
  __shared__ int wtot[4];
  __shared__ float s_pos[3];
  __shared__ float s_sel[3];

  // aliases — live only after the rank/score pass (barrier-separated)
  float* cscore = (float*)base;            // 768 (base: 2048 int slots)
  float* cx     = (float*)base + 768;      // 768
  int*   crank  = (int*)sorted;            // 768 (sorted: 4096 slots)
  float* redf   = sorted + 1024;           // 256
  int*   redi   = (int*)(sorted + 1280);   // 256
  int*   redi2  = (int*)(sorted + 1536);   // 256

  const int i = blockIdx.x;
  const int tid = threadIdx.x;
  const int lane = tid & 63, wid = tid >> 6;
  const float* row = dist + (size_t)i * NROW;
  const int gbase = i & ~3;

  // ---- load 16 values ----
  float x[16];
  {
    const float4* r4 = (const float4*)row;
#pragma unroll
    for (int q4 = 0; q4 < 4; ++q4) {
      float4 f = r4[tid * 4 + q4];
      x[q4 * 4 + 0] = f.x; x[q4 * 4 + 1] = f.y;
      x[q4 * 4 + 2] = f.z; x[q4 * 4 + 3] = f.w;
    }
  }

  // ---- positives from the owning thread's registers (no global re-reads) ----
  if (tid == (gbase >> 4)) {
    float p[3]; int np = 0;
#pragma unroll
    for (int qq = 0; qq < 4; ++qq) {
      int j = gbase + qq;
      if (j != i) p[np++] = x[j & 15];
    }
    float a = p[0], b = p[1], c = p[2], t_;
    if (a > b) { t_ = a; a = b; b = t_; }
    if (b > c) { t_ = b; b = c; c = t_; }
    if (a > b) { t_ = a; a = b; b = t_; }
    s_pos[0] = a; s_pos[1] = b; s_pos[2] = c;
  }

  // ---- mask same-class block to INF ----
#pragma unroll
  for (int qq = 0; qq < 16; ++qq) {
    int j = tid * 16 + qq;
    if ((j >> 2) == (i >> 2)) x[qq] = INF_VAL;
  }

  // ---- mean ----
  float ls = 0.f;
#pragma unroll
  for (int qq = 0; qq < 16; ++qq) if (x[qq] < 1e29f) ls += x[qq];
  for (int o = 32; o > 0; o >>= 1) ls += __shfl_down(ls, o);
  if (lane == 0) wredf[wid] = ls;
  __syncthreads();
  const float negsum = wredf[0] + wredf[1] + wredf[2] + wredf[3];
  const float mean = negsum / (float)KNEG;

  // ---- variance (two-pass, matches ref) ----
  float ls2 = 0.f;
#pragma unroll
  for (int qq = 0; qq < 16; ++qq)
    if (x[qq] < 1e29f) { float z = x[qq] - mean; ls2 += z * z; }
  for (int o = 32; o > 0; o >>= 1) ls2 += __shfl_down(ls2, o);
  if (lane == 0) wredf[4 + wid] = ls2;
  __syncthreads();
  const float var = (wredf[4] + wredf[5] + wredf[6] + wredf[7]) / (float)KNEG;
  const float stdv = sqrtf(var);
  const float rdenom = __frcp_rn(2.0f * stdv * stdv);
  const float invw = 256.0f / stdv;   // +-4 sigma across 2048 buckets

  // ---- histogram (linear buckets) ----
  {
    int4* b4 = (int4*)base;
    b4[tid] = (int4){0, 0, 0, 0};
    b4[tid + 256] = (int4){0, 0, 0, 0};
  }
  __syncthreads();
  int bkt[16];
#pragma unroll
  for (int qq = 0; qq < 16; ++qq) {
    bkt[qq] = bucket_lin(x[qq], mean, invw);
    atomicAdd(&base[bkt[qq]], 1);
  }
  __syncthreads();

  // ---- exclusive scan over 2048 buckets (8/thread + wave shfl) ----
  int c8[8]; int lsum = 0;
#pragma unroll
  for (int qq = 0; qq < 8; ++qq) {
    int t_ = base[tid * 8 + qq];
    c8[qq] = lsum; lsum += t_;
  }
  int incl = lsum;
  for (int off = 1; off < 64; off <<= 1) {
    int o = __shfl_up(incl, off);
    if (lane >= off) incl += o;
  }
  if (lane == 63) wtot[wid] = incl;
  __syncthreads();
  int excl = incl - lsum;
#pragma unroll
  for (int w = 0; w < 4; ++w) if (w < wid) excl += wtot[w];
#pragma unroll
  for (int qq = 0; qq < 8; ++qq) base[tid * 8 + qq] = excl + c8[qq];
  __syncthreads();

  // ---- scatter (base[b] becomes bucket END) ----
#pragma unroll
  for (int qq = 0; qq < 16; ++qq) {
    int p = atomicAdd(&base[bkt[qq]], 1);
    sorted[p] = x[qq];
  }
  __syncthreads();

  // ---- rank/score/top-3 ----
  const uint32_t fbase = (uint32_t)i * (uint32_t)KNEG;
  const float* grow = G ? (G + fbase) : nullptr;
  float t0s = -1e38f, t1s = -1e38f, t2s = -1e38f;
  int   t0r = 0x7fffffff, t1r = 0x7fffffff, t2r = 0x7fffffff;
  float t0x = 0.f, t1x = 0.f, t2x = 0.f;
#pragma unroll
  for (int qq = 0; qq < 16; ++qq) {
    int p = tid + 256 * qq;
    float xv = sorted[p];
    int rank = p;
    // only qq 0,1,14,15 can ever hit the tail ranges — guard folds away
    // for the other 12 unrolled iterations at compile time
    if ((qq <= 1 || qq >= 14) && (p < PLO || p >= PHI)) {
      int b = bucket_lin(xv, mean, invw);
      int s0 = (b == 0) ? 0 : base[b - 1];
      int e0 = base[b];
      int c = 0;
      for (int u = s0; u < e0; ++u) {
        float o = sorted[u];
        c += (o < xv || (o == xv && u < p)) ? 1 : 0;
      }
      rank = s0 + c;
    }
    if (rank < KNEG) {
      float z = xv - mean;
      float gv = grow ? grow[rank] : gumbel_ref(fbase + (uint32_t)rank);
      float sv = fmaf(z * z, rdenom, gv);
      if (sv > t2s || (sv == t2s && rank < t2r)) {
        t2s = sv; t2r = rank; t2x = xv;
        if (t2s > t1s || (t2s == t1s && t2r < t1r)) {
          float ts = t1s; int tr = t1r; float tx = t1x;
          t1s = t2s; t1r = t2r; t1x = t2x; t2s = ts; t2r = tr; t2x = tx;
        }
        if (t1s > t0s || (t1s == t0s && t1r < t0r)) {
          float ts = t0s; int tr = t0r; float tx = t0x;
          t0s = t1s; t0r = t1r; t0x = t1x; t1s = ts; t1r = tr; t1x = tx;
        }
      }
    }
  }
  __syncthreads();  // sorted/base reads done; aliases become live

  cscore[tid * 3 + 0] = t0s; crank[tid * 3 + 0] = t0r; cx[tid * 3 + 0] = t0x;
  cscore[tid * 3 + 1] = t1s; crank[tid * 3 + 1] = t1r; cx[tid * 3 + 1] = t1x;
  cscore[tid * 3 + 2] = t2s; crank[tid * 3 + 2] = t2r; cx[tid * 3 + 2] = t2x;
  __syncthreads();

  // ---- block top-3 over 768 candidates (score desc, rank asc) ----
  for (int t = 0; t < 3; ++t) {
    float bs = -1e38f; int br = 0x7fffffff; int bidx = 0;
    for (int k = tid; k < 768; k += 256) {
      float s_ = cscore[k]; int r_ = crank[k];
      if (s_ > bs || (s_ == bs && r_ < br)) { bs = s_; br = r_; bidx = k; }
    }
    redf[tid] = bs; redi[tid] = br; redi2[tid] = bidx;
    __syncthreads();
    if (tid < 64) {
      float s0_ = redf[tid]; int r0_ = redi[tid]; int i0_ = redi2[tid];
#pragma unroll
      for (int o = 64; o < 256; o += 64) {
        float s1 = redf[tid + o]; int r1 = redi[tid + o];
        if (s1 > s0_ || (s1 == s0_ && r1 < r0_)) {
          s0_ = s1; r0_ = r1; i0_ = redi2[tid + o];
        }
      }
      for (int off = 32; off > 0; off >>= 1) {
        float s1 = __shfl_down(s0_, off);
        int r1 = __shfl_down(r0_, off);
        int i1 = __shfl_down(i0_, off);
        if (s1 > s0_ || (s1 == s0_ && r1 < r0_)) { s0_ = s1; r0_ = r1; i0_ = i1; }
      }
      if (tid == 0) { s_sel[t] = cx[i0_]; cscore[i0_] = -1e38f; }
    }
    __syncthreads();
  }

  // ---- epilogue: one plain store per block, no atomics ----
  if (tid == 0) {
    float p0 = s_pos[0], p1 = s_pos[1], p2 = s_pos[2];
    float thr = p2 + 0.05f;
    float samp[3]; bool kept[3]; int cnt = 0;
#pragma unroll
    for (int t = 0; t < 3; ++t) {
      samp[t] = s_sel[t];
      kept[t] = samp[t] < thr;
      cnt += kept[t] ? 1 : 0;
    }
    bool any = cnt > 0;
    float pos_loss = 0.5f *
        (softplus_ref(-2.0f * (1.0f - p0)) + softplus_ref(-2.0f * (1.0f - p1)) +
         softplus_ref(-2.0f * (1.0f - p2))) / 3.0f;
    float nsum = 0.0f;
#pragma unroll
    for (int t = 0; t < 3; ++t)
      if (kept[t]) nsum += softplus_ref(20.0f * (1.0f - samp[t]));
    float neg_loss = 0.05f * nsum / (float)(cnt > 0 ? cnt : 1);
    float row_loss = any ? (pos_loss + neg_loss) : 0.0f;
    int first = kept[0] ? 0 : (kept[1] ? 1 : (kept[2] ? 2 : 0));
    float neg0 = samp[first];
    float errv = (any && (p0 < neg0 - 0.1f)) ? 1.0f : 0.0f;
    float4 pr;
    pr.x = row_loss; pr.y = errv; pr.z = p0 + p1 + p2; pr.w = negsum;
    part[i] = pr;
  }
}

// ---------------- reduce: 4096 float4 partials -> 4 outputs ----------------
__global__ __launch_bounds__(256) void reduce_kernel(const float4* __restrict__ part,
                                                     float* __restrict__ out) {
  __shared__ double wsum[4][4];
  const int tid = threadIdx.x;
  const int lane = tid & 63, wid = tid >> 6;
  double s0 = 0.0, s1 = 0.0, s2 = 0.0, s3 = 0.0;
  for (int k = tid; k < NROW; k += 256) {
    float4 v = part[k];
    s0 += (double)v.x; s1 += (double)v.y; s2 += (double)v.z; s3 += (double)v.w;
  }
  for (int o = 32; o > 0; o >>= 1) {
    s0 += __shfl_down(s0, o); s1 += __shfl_down(s1, o);
    s2 += __shfl_down(s2, o); s3 += __shfl_down(s3, o);
  }
  if (lane == 0) {
    wsum[wid][0] = s0; wsum[wid][1] = s1; wsum[wid][2] = s2; wsum[wid][3] = s3;
  }
  __syncthreads();
  if (tid == 0) {
    double a0 = wsum[0][0] + wsum[1][0] + wsum[2][0] + wsum[3][0];
    double a1 = wsum[0][1] + wsum[1][1] + wsum[2][1] + wsum[3][1];
    double a2 = wsum[0][2] + wsum[1][2] + wsum[2][2] + wsum[3][2];
    double a3 = wsum[0][3] + wsum[1][3] + wsum[2][3] + wsum[3][3];
    out[0] = (float)(a0 / (double)NROW);
    out[1] = (float)(1.0 - a1 / (double)NROW);
    out[2] = (float)(a2 / ((double)NROW * 3.0));
    out[3] = (float)(a3 / ((double)NROW * (double)KNEG));
  }
}

extern "C" void kernel_launch(void* const* d_in, const int* in_sizes, int n_in,
                              void* d_out, int out_size, void* d_ws, size_t ws_size,
                              hipStream_t stream) {
  (void)in_sizes; (void)n_in; (void)out_size;
  const float* X = (const float*)d_in[0];
  float* out = (float*)d_out;
  char* ws = (char*)d_ws;

  float* dist = (float*)ws;                                        // 64 MiB
  size_t off = (size_t)NROW * NROW * sizeof(float);
  float* sq = (float*)(ws + off);            off += NROW * sizeof(float);
  ushort* Xbf = (ushort*)(ws + off);         off += (size_t)NROW * NDIM * sizeof(ushort);
  float4* part = (float4*)(ws + off);        off += (size_t)NROW * sizeof(float4);
  // Gumbel table (64 MB) — only if workspace allows; else inline fallback
  float* G = nullptr;
  if (ws_size >= off + GTOT * sizeof(float)) G = (float*)(ws + off);

  prep_kernel<<<NROW, 64, 0, stream>>>(X, sq, Xbf);
  if (G) gumbel_kernel<<<KNEG, 256, 0, stream>>>(G);
  dim3 gb(NROW / 128, NROW / 128);
  dist_mfma<<<gb, 256, 0, stream>>>(Xbf, sq, dist);
  row_kernel<<<NROW, 256, 0, stream>>>(dist, G, part);
  reduce_kernel<<<1, 256, 0, stream>>>(part, out);
}

// Round 10
// 180.422 us; speedup vs baseline: 1.8883x; 1.0243x over previous
//
#include <hip/hip_runtime.h>
#include <stdint.h>

#define NROW 4096
#define NDIM 128
#define KNEG 4092
#define INF_VAL 1e30f
#define BUCKETS 2048
#define PLO 384
#define PHI 3712
#define GTOT ((size_t)NROW * (size_t)KNEG)   // 16,760,832 = 4092 * 4096
#define DISTBLKS 1024                         // 32x32 tiles
#define GUMBLKS KNEG                          // 4092 gumbel blocks

typedef __attribute__((ext_vector_type(8))) short short8;
typedef __attribute__((ext_vector_type(4))) float f32x4;

// ---------------- Threefry-2x32-20, key = (0, 42) ----------------
__device__ __forceinline__ uint32_t rotl32(uint32_t v, int d) {
  return (v << d) | (v >> (32 - d));
}

__device__ __forceinline__ void threefry2x32(uint32_t x0, uint32_t x1,
                                             uint32_t& y0, uint32_t& y1) {
  const uint32_t k0 = 0u, k1 = 42u;
  const uint32_t k2 = 0x1BD11BDAu ^ k0 ^ k1;
  uint32_t v0 = x0 + k0, v1 = x1 + k1;
#define TF_R(r) v0 += v1; v1 = rotl32(v1, r); v1 ^= v0;
  TF_R(13) TF_R(15) TF_R(26) TF_R(6)
  v0 += k1; v1 += k2 + 1u;
  TF_R(17) TF_R(29) TF_R(16) TF_R(24)
  v0 += k2; v1 += k0 + 2u;
  TF_R(13) TF_R(15) TF_R(26) TF_R(6)
  v0 += k0; v1 += k1 + 3u;
  TF_R(17) TF_R(29) TF_R(16) TF_R(24)
  v0 += k1; v1 += k2 + 4u;
  TF_R(13) TF_R(15) TF_R(26) TF_R(6)
  v0 += k2; v1 += k0 + 5u;
#undef TF_R
  y0 = v0; y1 = v1;
}

// partitionable threefry, bits = y1 — verified R1; __logf verified R3
__device__ __forceinline__ float gumbel_ref(uint32_t f) {
  uint32_t y0, y1;
  threefry2x32(0u, f, y0, y1);
  uint32_t m = y1 >> 9;
  float u;
  if (m == 0u) u = 1.17549435e-38f;
  else u = __uint_as_float(m | 0x3f800000u) - 1.0f;
  return -__logf(-__logf(u));
}

__device__ __forceinline__ float softplus_ref(float x) {
  return fmaxf(x, 0.0f) + log1pf(expf(-fabsf(x)));
}

// linear-in-z monotone key (5 instr). Float-clamp BEFORE cvt so INF -> 2047.
__device__ __forceinline__ int bucket_lin(float x, float mean, float invw) {
  float b = (x - mean) * invw + 1024.0f;
  b = fminf(fmaxf(b, 0.0f), 2047.0f);
  return (int)b;
}

// ---------------- kernel A: sumsq + fp32->bf16 convert ----------------
__global__ __launch_bounds__(64) void prep_kernel(const float* __restrict__ X,
                                                  float* __restrict__ sq,
                                                  ushort* __restrict__ Xbf) {
  int i = blockIdx.x;
  int lane = threadIdx.x;
  float2 v = ((const float2*)(X + (size_t)i * NDIM))[lane];
  float s = v.x * v.x + v.y * v.y;
  for (int o = 32; o > 0; o >>= 1) s += __shfl_down(s, o);
  if (lane == 0) sq[i] = s;
  uint32_t ux = __float_as_uint(v.x);
  uint32_t uy = __float_as_uint(v.y);
  ux += 0x7fffu + ((ux >> 16) & 1u);
  uy += 0x7fffu + ((uy >> 16) & 1u);
  ushort2 h;
  h.x = (ushort)(ux >> 16);
  h.y = (ushort)(uy >> 16);
  ((ushort2*)(Xbf + (size_t)i * NDIM))[lane] = h;
}

// ---------------- fused kernel B: dist tiles + gumbel table in ONE launch ----
// blocks [0,1024): 128x128 bf16-MFMA dist tile; blocks [1024,5116): gumbel
// chunk. Both independent of each other; fusing removes gumbel's serial slot
// (concurrent fill) and one launch gap.
#define DSTR 68
__global__ __launch_bounds__(256) void dist_gumbel(const ushort* __restrict__ Xbf,
                                                   const float* __restrict__ sq,
                                                   float* __restrict__ dist,
                                                   float* __restrict__ g) {
  __shared__ ushort Als[128 * DSTR];
  __shared__ ushort Bls[128 * DSTR];
  const int tid = threadIdx.x;

  if (blockIdx.x >= DISTBLKS) {
    // ---------------- gumbel branch ----------------
    if (g) {
      uint32_t b0 = (uint32_t)(blockIdx.x - DISTBLKS) * 4096u;
#pragma unroll
      for (int q = 0; q < 4; ++q) {
        uint32_t f0 = b0 + (uint32_t)q * 1024u + (uint32_t)tid * 4u;
        float4 v;
        v.x = gumbel_ref(f0 + 0u);
        v.y = gumbel_ref(f0 + 1u);
        v.z = gumbel_ref(f0 + 2u);
        v.w = gumbel_ref(f0 + 3u);
        *(float4*)(g + f0) = v;
      }
    }
    return;
  }

  // ---------------- dist branch ----------------
  const int bi = blockIdx.x >> 5, bj = blockIdx.x & 31;
  const int wave = tid >> 6, lane = tid & 63;
  const int q = lane >> 4, ln = lane & 15;
  const ushort* Ag = Xbf + (size_t)bi * 128 * NDIM;
  const ushort* Bg = Xbf + (size_t)bj * 128 * NDIM;

  f32x4 acc[8][2];
#pragma unroll
  for (int mt = 0; mt < 8; ++mt)
#pragma unroll
    for (int nt = 0; nt < 2; ++nt) acc[mt][nt] = (f32x4){0.f, 0.f, 0.f, 0.f};

  for (int kh = 0; kh < 2; ++kh) {
    if (kh) __syncthreads();
#pragma unroll
    for (int t = 0; t < 4; ++t) {
      int c = tid + 256 * t;
      int r = c >> 3, k8 = (c & 7) << 3;
      *(short8*)&Als[r * DSTR + k8] =
          *(const short8*)(Ag + (size_t)r * NDIM + kh * 64 + k8);
      *(short8*)&Bls[r * DSTR + k8] =
          *(const short8*)(Bg + (size_t)r * NDIM + kh * 64 + k8);
    }
    __syncthreads();
#pragma unroll
    for (int k0 = 0; k0 < 64; k0 += 32) {
      int kf = k0 + q * 8;
      short8 a[8], b[2];
#pragma unroll
      for (int mt = 0; mt < 8; ++mt)
        a[mt] = *(const short8*)&Als[(mt * 16 + ln) * DSTR + kf];
      // lane owns ADJACENT cols 2*ln, 2*ln+1 (monotone remap of the 16-col
      // fragment) -> dwordx2 epilogue stores. Bank: stride 68 dw -> 4ln%32,
      // 2-way = free.
#pragma unroll
      for (int nt = 0; nt < 2; ++nt)
        b[nt] = *(const short8*)&Bls[(wave * 32 + 2 * ln + nt) * DSTR + kf];
#pragma unroll
      for (int mt = 0; mt < 8; ++mt)
#pragma unroll
        for (int nt = 0; nt < 2; ++nt)
          acc[mt][nt] = __builtin_amdgcn_mfma_f32_16x16x32_bf16(
              a[mt], b[nt], acc[mt][nt], 0, 0, 0);
    }
  }

  const int jcol = bj * 128 + wave * 32 + 2 * ln;
  float sqj0 = sq[jcol], sqj1 = sq[jcol + 1];
#pragma unroll
  for (int mt = 0; mt < 8; ++mt) {
    int ibase = bi * 128 + mt * 16 + q * 4;
#pragma unroll
    for (int r = 0; r < 4; ++r) {
      int i = ibase + r;
      float sqi = sq[i];
      float2 o;
      o.x = sqrtf(fmaxf(sqi + sqj0 - 2.0f * acc[mt][0][r], 1e-12f));
      o.y = sqrtf(fmaxf(sqi + sqj1 - 2.0f * acc[mt][1][r], 1e-12f));
      *(float2*)(dist + (size_t)i * NROW + jcol) = o;
    }
  }
}

// ---------------- kernel C: per-row rank + sample + loss ----------------
__global__ __launch_bounds__(256) void row_kernel(const float* __restrict__ dist,
                                                  const float* __restrict__ G,
                                                  float4* __restrict__ part) {
  __shared__ alignas(16) float sorted[NROW];   // 16 KB
  __shared__ alignas(16) int base[BUCKETS];    // 8 KB (bucket ENDs after scatter)
  __shared__ float wredf[8];
  __shared__ int wtot[4];
  __shared__ float s_pos[3];
  __shared__ float s_sel[3];

  // aliases — live only after the rank/score pass (barrier-separated)
  float* cscore = (float*)base;            // 768 (base: 2048 int slots)
  float* cx     = (float*)base + 768;      // 768
  int*   crank  = (int*)sorted;            // 768 (sorted: 4096 slots)
  float* redf   = sorted + 1024;           // 256
  int*   redi   = (int*)(sorted + 1280);   // 256
  int*   redi2  = (int*)(sorted + 1536);   // 256

  const int i = blockIdx.x;
  const int tid = threadIdx.x;
  const int lane = tid & 63, wid = tid >> 6;
  const float* row = dist + (size_t)i * NROW;
  const int gbase = i & ~3;

  // ---- load 16 values ----
  float x[16];
  {
    const float4* r4 = (const float4*)row;
#pragma unroll
    for (int q4 = 0; q4 < 4; ++q4) {
      float4 f = r4[tid * 4 + q4];
      x[q4 * 4 + 0] = f.x; x[q4 * 4 + 1] = f.y;
      x[q4 * 4 + 2] = f.z; x[q4 * 4 + 3] = f.w;
    }
  }

  // ---- positives from the owning thread's registers ----
  if (tid == (gbase >> 4)) {
    float p[3]; int np = 0;
#pragma unroll
    for (int qq = 0; qq < 4; ++qq) {
      int j = gbase + qq;
      if (j != i) p[np++] = x[j & 15];
    }
    float a = p[0], b = p[1], c = p[2], t_;
    if (a > b) { t_ = a; a = b; b = t_; }
    if (b > c) { t_ = b; b = c; c = t_; }
    if (a > b) { t_ = a; a = b; b = t_; }
    s_pos[0] = a; s_pos[1] = b; s_pos[2] = c;
  }

  // ---- mask same-class block to INF ----
#pragma unroll
  for (int qq = 0; qq < 16; ++qq) {
    int j = tid * 16 + qq;
    if ((j >> 2) == (i >> 2)) x[qq] = INF_VAL;
  }

  // ---- mean ----
  float ls = 0.f;
#pragma unroll
  for (int qq = 0; qq < 16; ++qq) if (x[qq] < 1e29f) ls += x[qq];
  for (int o = 32; o > 0; o >>= 1) ls += __shfl_down(ls, o);
  if (lane == 0) wredf[wid] = ls;
  __syncthreads();
  const float negsum = wredf[0] + wredf[1] + wredf[2] + wredf[3];
  const float mean = negsum / (float)KNEG;

  // ---- variance (two-pass, matches ref) ----
  float ls2 = 0.f;
#pragma unroll
  for (int qq = 0; qq < 16; ++qq)
    if (x[qq] < 1e29f) { float z = x[qq] - mean; ls2 += z * z; }
  for (int o = 32; o > 0; o >>= 1) ls2 += __shfl_down(ls2, o);
  if (lane == 0) wredf[4 + wid] = ls2;
  __syncthreads();
  const float var = (wredf[4] + wredf[5] + wredf[6] + wredf[7]) / (float)KNEG;
  const float stdv = sqrtf(var);
  const float rdenom = __frcp_rn(2.0f * stdv * stdv);
  const float invw = 256.0f / stdv;   // +-4 sigma across 2048 buckets

  // ---- histogram (linear buckets) ----
  {
    int4* b4 = (int4*)base;
    b4[tid] = (int4){0, 0, 0, 0};
    b4[tid + 256] = (int4){0, 0, 0, 0};
  }
  __syncthreads();
  int bkt[16];
#pragma unroll
  for (int qq = 0; qq < 16; ++qq) {
    bkt[qq] = bucket_lin(x[qq], mean, invw);
    atomicAdd(&base[bkt[qq]], 1);
  }
  __syncthreads();

  // ---- exclusive scan over 2048 buckets (8/thread + wave shfl) ----
  int c8[8]; int lsum = 0;
#pragma unroll
  for (int qq = 0; qq < 8; ++qq) {
    int t_ = base[tid * 8 + qq];
    c8[qq] = lsum; lsum += t_;
  }
  int incl = lsum;
  for (int off = 1; off < 64; off <<= 1) {
    int o = __shfl_up(incl, off);
    if (lane >= off) incl += o;
  }
  if (lane == 63) wtot[wid] = incl;
  __syncthreads();
  int excl = incl - lsum;
#pragma unroll
  for (int w = 0; w < 4; ++w) if (w < wid) excl += wtot[w];
#pragma unroll
  for (int qq = 0; qq < 8; ++qq) base[tid * 8 + qq] = excl + c8[qq];
  __syncthreads();

  // ---- scatter (base[b] becomes bucket END) ----
#pragma unroll
  for (int qq = 0; qq < 16; ++qq) {
    int p = atomicAdd(&base[bkt[qq]], 1);
    sorted[p] = x[qq];
  }
  __syncthreads();

  // ---- rank/score/top-3 ----
  const uint32_t fbase = (uint32_t)i * (uint32_t)KNEG;
  const float* grow = G ? (G + fbase) : nullptr;
  float t0s = -1e38f, t1s = -1e38f, t2s = -1e38f;
  int   t0r = 0x7fffffff, t1r = 0x7fffffff, t2r = 0x7fffffff;
  float t0x = 0.f, t1x = 0.f, t2x = 0.f;
#pragma unroll
  for (int qq = 0; qq < 16; ++qq) {
    int p = tid + 256 * qq;
    float xv = sorted[p];
    int rank = p;
    // only qq 0,1,14,15 can ever hit the tail ranges — guard folds away
    if ((qq <= 1 || qq >= 14) && (p < PLO || p >= PHI)) {
      int b = bucket_lin(xv, mean, invw);
      int s0 = (b == 0) ? 0 : base[b - 1];
      int e0 = base[b];
      int c = 0;
      for (int u = s0; u < e0; ++u) {
        float o = sorted[u];
        c += (o < xv || (o == xv && u < p)) ? 1 : 0;
      }
      rank = s0 + c;
    }
    if (rank < KNEG) {
      float z = xv - mean;
      float gv = grow ? grow[rank] : gumbel_ref(fbase + (uint32_t)rank);
      float sv = fmaf(z * z, rdenom, gv);
      if (sv > t2s || (sv == t2s && rank < t2r)) {
        t2s = sv; t2r = rank; t2x = xv;
        if (t2s > t1s || (t2s == t1s && t2r < t1r)) {
          float ts = t1s; int tr = t1r; float tx = t1x;
          t1s = t2s; t1r = t2r; t1x = t2x; t2s = ts; t2r = tr; t2x = tx;
        }
        if (t1s > t0s || (t1s == t0s && t1r < t0r)) {
          float ts = t0s; int tr = t0r; float tx = t0x;
          t0s = t1s; t0r = t1r; t0x = t1x; t1s = ts; t1r = tr; t1x = tx;
        }
      }
    }
  }
  __syncthreads();  // sorted/base reads done; aliases become live

  cscore[tid * 3 + 0] = t0s; crank[tid * 3 + 0] = t0r; cx[tid * 3 + 0] = t0x;
  cscore[tid * 3 + 1] = t1s; crank[tid * 3 + 1] = t1r; cx[tid * 3 + 1] = t1x;
  cscore[tid * 3 + 2] = t2s; crank[tid * 3 + 2] = t2r; cx[tid * 3 + 2] = t2x;
  __syncthreads();

  // ---- block top-3 over 768 candidates (score desc, rank asc) ----
  for (int t = 0; t < 3; ++t) {
    float bs = -1e38f; int br = 0x7fffffff; int bidx = 0;
    for (int k = tid; k < 768; k += 256) {
      float s_ = cscore[k]; int r_ = crank[k];
      if (s_ > bs || (s_ == bs && r_ < br)) { bs = s_; br = r_; bidx = k; }
    }
    redf[tid] = bs; redi[tid] = br; redi2[tid] = bidx;
    __syncthreads();
    if (tid < 64) {
      float s0_ = redf[tid]; int r0_ = redi[tid]; int i0_ = redi2[tid];
#pragma unroll
      for (int o = 64; o < 256; o += 64) {
        float s1 = redf[tid + o]; int r1 = redi[tid + o];
        if (s1 > s0_ || (s1 == s0_ && r1 < r0_)) {
          s0_ = s1; r0_ = r1; i0_ = redi2[tid + o];
        }
      }
      for (int off = 32; off > 0; off >>= 1) {
        float s1 = __shfl_down(s0_, off);
        int r1 = __shfl_down(r0_, off);
        int i1 = __shfl_down(i0_, off);
        if (s1 > s0_ || (s1 == s0_ && r1 < r0_)) { s0_ = s1; r0_ = r1; i0_ = i1; }
      }
      if (tid == 0) { s_sel[t] = cx[i0_]; cscore[i0_] = -1e38f; }
    }
    __syncthreads();
  }

  // ---- epilogue: one plain store per block, no atomics ----
  if (tid == 0) {
    float p0 = s_pos[0], p1 = s_pos[1], p2 = s_pos[2];
    float thr = p2 + 0.05f;
    float samp[3]; bool kept[3]; int cnt = 0;
#pragma unroll
    for (int t = 0; t < 3; ++t) {
      samp[t] = s_sel[t];
      kept[t] = samp[t] < thr;
      cnt += kept[t] ? 1 : 0;
    }
    bool any = cnt > 0;
    float pos_loss = 0.5f *
        (softplus_ref(-2.0f * (1.0f - p0)) + softplus_ref(-2.0f * (1.0f - p1)) +
         softplus_ref(-2.0f * (1.0f - p2))) / 3.0f;
    float nsum = 0.0f;
#pragma unroll
    for (int t = 0; t < 3; ++t)
      if (kept[t]) nsum += softplus_ref(20.0f * (1.0f - samp[t]));
    float neg_loss = 0.05f * nsum / (float)(cnt > 0 ? cnt : 1);
    float row_loss = any ? (pos_loss + neg_loss) : 0.0f;
    int first = kept[0] ? 0 : (kept[1] ? 1 : (kept[2] ? 2 : 0));
    float neg0 = samp[first];
    float errv = (any && (p0 < neg0 - 0.1f)) ? 1.0f : 0.0f;
    float4 pr;
    pr.x = row_loss; pr.y = errv; pr.z = p0 + p1 + p2; pr.w = negsum;
    part[i] = pr;
  }
}

// ---------------- reduce: 4096 float4 partials -> 4 outputs ----------------
__global__ __launch_bounds__(256) void reduce_kernel(const float4* __restrict__ part,
                                                     float* __restrict__ out) {
  __shared__ double wsum[4][4];
  const int tid = threadIdx.x;
  const int lane = tid & 63, wid = tid >> 6;
  double s0 = 0.0, s1 = 0.0, s2 = 0.0, s3 = 0.0;
  for (int k = tid; k < NROW; k += 256) {
    float4 v = part[k];
    s0 += (double)v.x; s1 += (double)v.y; s2 += (double)v.z; s3 += (double)v.w;
  }
  for (int o = 32; o > 0; o >>= 1) {
    s0 += __shfl_down(s0, o); s1 += __shfl_down(s1, o);
    s2 += __shfl_down(s2, o); s3 += __shfl_down(s3, o);
  }
  if (lane == 0) {
    wsum[wid][0] = s0; wsum[wid][1] = s1; wsum[wid][2] = s2; wsum[wid][3] = s3;
  }
  __syncthreads();
  if (tid == 0) {
    double a0 = wsum[0][0] + wsum[1][0] + wsum[2][0] + wsum[3][0];
    double a1 = wsum[0][1] + wsum[1][1] + wsum[2][1] + wsum[3][1];
    double a2 = wsum[0][2] + wsum[1][2] + wsum[2][2] + wsum[3][2];
    double a3 = wsum[0][3] + wsum[1][3] + wsum[2][3] + wsum[3][3];
    out[0] = (float)(a0 / (double)NROW);
    out[1] = (float)(1.0 - a1 / (double)NROW);
    out[2] = (float)(a2 / ((double)NROW * 3.0));
    out[3] = (float)(a3 / ((double)NROW * (double)KNEG));
  }
}

extern "C" void kernel_launch(void* const* d_in, const int* in_sizes, int n_in,
                              void* d_out, int out_size, void* d_ws, size_t ws_size,
                              hipStream_t stream) {
  (void)in_sizes; (void)n_in; (void)out_size;
  const float* X = (const float*)d_in[0];
  float* out = (float*)d_out;
  char* ws = (char*)d_ws;

  float* dist = (float*)ws;                                        // 64 MiB
  size_t off = (size_t)NROW * NROW * sizeof(float);
  float* sq = (float*)(ws + off);            off += NROW * sizeof(float);
  ushort* Xbf = (ushort*)(ws + off);         off += (size_t)NROW * NDIM * sizeof(ushort);
  float4* part = (float4*)(ws + off);        off += (size_t)NROW * sizeof(float4);
  // Gumbel table (64 MB) — only if workspace allows; else inline fallback
  float* G = nullptr;
  if (ws_size >= off + GTOT * sizeof(float)) G = (float*)(ws + off);

  prep_kernel<<<NROW, 64, 0, stream>>>(X, sq, Xbf);
  dist_gumbel<<<DISTBLKS + (G ? GUMBLKS : 0), 256, 0, stream>>>(Xbf, sq, dist, G);
  row_kernel<<<NROW, 256, 0, stream>>>(dist, G, part);
  reduce_kernel<<<1, 256, 0, stream>>>(part, out);
}